// Round 3
// baseline (88.004 us; speedup 1.0000x reference)
//
#include <hip/hip_runtime.h>

#define BLOCK 256

__device__ __forceinline__ int mbcnt64(unsigned long long m) {
    return __builtin_amdgcn_mbcnt_hi((unsigned int)(m >> 32),
           __builtin_amdgcn_mbcnt_lo((unsigned int)m, 0));
}

// ---------------------------------------------------------------------------
// Per-(f,s) precompute body (fallback 3-kernel path).
// ---------------------------------------------------------------------------
__device__ __forceinline__ void face_pre_body(
        int idx,
        const float* __restrict__ verts, const int* __restrict__ faces,
        const float* __restrict__ alpha, const float* __restrict__ beta,
        int S,
        float4* __restrict__ cent, float4* __restrict__ gg,
        float4* __restrict__ spts) {
    int f = idx / S;
    int s = idx - f * S;

    int i0 = faces[3 * f + 0];
    int i1 = faces[3 * f + 1];
    int i2 = faces[3 * f + 2];
    float ax = verts[3 * i0 + 0], ay = verts[3 * i0 + 1], az = verts[3 * i0 + 2];
    float bx = verts[3 * i1 + 0], by = verts[3 * i1 + 1], bz = verts[3 * i1 + 2];
    float cx = verts[3 * i2 + 0], cy = verts[3 * i2 + 1], cz = verts[3 * i2 + 2];

    float al = alpha[idx];
    float be = beta[idx];
    float ga = 1.0f - al - be;
    spts[idx] = make_float4(al * ax + be * bx + ga * cx,
                            al * ay + be * by + ga * cy,
                            al * az + be * bz + ga * cz, 0.0f);

    if (s == 0) {
        float e0x = bx - ax, e0y = by - ay, e0z = bz - az;
        float e1x = cx - ax, e1y = cy - ay, e1z = cz - az;

        float d00 = e0x * e0x + e0y * e0y + e0z * e0z;
        float d01 = e0x * e1x + e0y * e1y + e0z * e1z;
        float d11 = e1x * e1x + e1y * e1y + e1z * e1z;
        float inv = 1.0f / (d00 * d11 - d01 * d01);
        float A = d11 * inv, B = d01 * inv, C = d00 * inv;

        float w1e0 = ax * e0x + ay * e0y + az * e0z;
        float w1e1 = ax * e1x + ay * e1y + az * e1z;

        const float third = 1.0f / 3.0f;
        cent[f] = make_float4((ax + bx + cx) * third,
                              (ay + by + cy) * third,
                              (az + bz + cz) * third, 0.0f);
        gg[2 * f + 0] = make_float4(A * e0x - B * e1x, A * e0y - B * e1y,
                                    A * e0z - B * e1z, B * w1e1 - A * w1e0);
        gg[2 * f + 1] = make_float4(C * e1x - B * e0x, C * e1y - B * e0y,
                                    C * e1z - B * e0z, B * w1e0 - C * w1e1);
    }
}

__global__ void face_pre_kernel(const float* __restrict__ verts,
                                const int* __restrict__ faces,
                                const float* __restrict__ alpha,
                                const float* __restrict__ beta,
                                int F, int S,
                                float4* __restrict__ cent,
                                float4* __restrict__ gg,
                                float4* __restrict__ spts) {
    int idx = blockIdx.x * blockDim.x + threadIdx.x;
    if (idx >= F * S) return;
    face_pre_body(idx, verts, faces, alpha, beta, S, cent, gg, spts);
}

// ---------------------------------------------------------------------------
// Depth-2 pipelined walk of one wave-private queue segment.
// gg may point to global memory (fallback path) or LDS (fused path).
// ---------------------------------------------------------------------------
template <int SS>
__device__ __forceinline__ int walk_queue(const int* s_queue, int wbase, int wlen,
                                          int lane,
                                          const float4* __restrict__ gg,
                                          const float* sx, const float* sy,
                                          const float* sz) {
    int count = 0;
    const int nIter = (wlen + 63) >> 6;
    bool  v_cur = lane < wlen;
    int   j_cur = v_cur ? s_queue[wbase + lane] : 0;
    float4 a_cur, b_cur;
    if (v_cur) { a_cur = gg[2 * j_cur]; b_cur = gg[2 * j_cur + 1]; }
    for (int t = 0; t < nIter; ++t) {
        int   k_n = lane + (t + 1) * 64;
        bool  v_n = k_n < wlen;
        int   j_n = v_n ? s_queue[wbase + k_n] : 0;
        float4 a_n, b_n;
        if (v_n) { a_n = gg[2 * j_n]; b_n = gg[2 * j_n + 1]; }
        if (v_cur) {
            float best = -1.0f;
#pragma unroll
            for (int s = 0; s < SS; ++s) {
                float vv = fmaf(sz[s], a_cur.z,
                            fmaf(sy[s], a_cur.y, fmaf(sx[s], a_cur.x, a_cur.w)));
                float ww = fmaf(sz[s], b_cur.z,
                            fmaf(sy[s], b_cur.y, fmaf(sx[s], b_cur.x, b_cur.w)));
                float uu = 1.0f - vv - ww;
                best = fmaxf(best, fminf(uu, fminf(vv, ww)));
            }
            count += (best >= 0.0f) ? 1 : 0;
        }
        v_cur = v_n; a_cur = a_n; b_cur = b_n;
    }
    return count;
}

// ---------------------------------------------------------------------------
// FULLY FUSED single-dispatch kernel (S==10, F<=1024). NO grid sync, and
// (round 3) NO cooperative launch: the only inter-block dependency is
// block 0 WAITING on the complement-pair publishes, which is deadlock-free
// under any block scheduling (only block 0 spins; blocks 1..N-1 run to
// completion on the remaining CUs regardless of residency).
//
//  - Each block privately recomputes all per-face data it needs
//    (stripe centroids in registers, gg[] for all F faces in LDS,
//    own-face samples uniformly per thread).
//  - Completion protocol: each block publishes partial[i] as a complement
//    pair (bits, ~bits) via agent-scope atomic stores; block 0 polls until
//    arrB[i] == ~arrA[i]. Uniform poison p can never satisfy p == ~p, and
//    any interleave that passes the check yields the true bits — no
//    zero-init needed. Block 0 then reduces in the exact FP order of the
//    old reduce_kernel.
//
// Dynamic LDS: 2F float4 (gg) + 8*SEG ints (queues) = 40 KiB at F=1024.
// ---------------------------------------------------------------------------
template <int SS>
__global__ void __launch_bounds__(BLOCK, 2)
fused2_kernel(const float* __restrict__ verts, const int* __restrict__ faces,
              const float* __restrict__ face_probs,
              const float* __restrict__ alpha, const float* __restrict__ beta,
              int F, int SEG,
              unsigned int* __restrict__ arrA, unsigned int* __restrict__ arrB,
              float* __restrict__ out, float invF) {
    extern __shared__ char smem[];
    float4* s_gg = (float4*)smem;                 // 2F float4
    int* s_queue = (int*)(s_gg + 2 * F);          // 8*SEG ints
    __shared__ int wave_cnt[2][BLOCK / 64];
    __shared__ float wave_sum[BLOCK / 64];

    const int tid = threadIdx.x;
    const int lane = tid & 63;
    const int wave = tid >> 6;
    const int iA = blockIdx.x * 2;
    const int iB = iA + 1;
    const bool hasB = (iB < F);
    const int iBs = hasB ? iB : iA;
    const float third = 1.0f / 3.0f;

    // ---- phase A: per-face cent (registers) + gg (LDS) ----
    float cxR[4], cyR[4], czR[4];
#pragma unroll
    for (int t = 0; t < 4; ++t) {
        int f = t * BLOCK + tid;
        if (f < F) {
            int i0 = faces[3 * f + 0];
            int i1 = faces[3 * f + 1];
            int i2 = faces[3 * f + 2];
            float ax = verts[3 * i0 + 0], ay = verts[3 * i0 + 1], az = verts[3 * i0 + 2];
            float bx = verts[3 * i1 + 0], by = verts[3 * i1 + 1], bz = verts[3 * i1 + 2];
            float cx = verts[3 * i2 + 0], cy = verts[3 * i2 + 1], cz = verts[3 * i2 + 2];

            float e0x = bx - ax, e0y = by - ay, e0z = bz - az;
            float e1x = cx - ax, e1y = cy - ay, e1z = cz - az;
            float d00 = e0x * e0x + e0y * e0y + e0z * e0z;
            float d01 = e0x * e1x + e0y * e1y + e0z * e1z;
            float d11 = e1x * e1x + e1y * e1y + e1z * e1z;
            float inv = 1.0f / (d00 * d11 - d01 * d01);
            float A = d11 * inv, B = d01 * inv, C = d00 * inv;
            float w1e0 = ax * e0x + ay * e0y + az * e0z;
            float w1e1 = ax * e1x + ay * e1y + az * e1z;

            cxR[t] = (ax + bx + cx) * third;
            cyR[t] = (ay + by + cy) * third;
            czR[t] = (az + bz + cz) * third;
            s_gg[2 * f + 0] = make_float4(A * e0x - B * e1x, A * e0y - B * e1y,
                                          A * e0z - B * e1z, B * w1e1 - A * w1e0);
            s_gg[2 * f + 1] = make_float4(C * e1x - B * e0x, C * e1y - B * e0y,
                                          C * e1z - B * e0z, B * w1e0 - C * w1e1);
        } else {
            cxR[t] = 1e30f; cyR[t] = 1e30f; czR[t] = 1e30f;
        }
    }

    // ---- own-face data: centroids + samples, uniform per thread ----
    float ciAx, ciAy, ciAz, ciBx, ciBy, ciBz;
    float sxA[SS], syA[SS], szA[SS], sxB[SS], syB[SS], szB[SS];
    {
        int i0 = faces[3 * iA + 0], i1 = faces[3 * iA + 1], i2 = faces[3 * iA + 2];
        float ax = verts[3 * i0 + 0], ay = verts[3 * i0 + 1], az = verts[3 * i0 + 2];
        float bx = verts[3 * i1 + 0], by = verts[3 * i1 + 1], bz = verts[3 * i1 + 2];
        float cx = verts[3 * i2 + 0], cy = verts[3 * i2 + 1], cz = verts[3 * i2 + 2];
        ciAx = (ax + bx + cx) * third;
        ciAy = (ay + by + cy) * third;
        ciAz = (az + bz + cz) * third;
#pragma unroll
        for (int s = 0; s < SS; ++s) {
            float al = alpha[iA * SS + s];
            float be = beta[iA * SS + s];
            float ga = 1.0f - al - be;
            sxA[s] = al * ax + be * bx + ga * cx;
            syA[s] = al * ay + be * by + ga * cy;
            szA[s] = al * az + be * bz + ga * cz;
        }
    }
    {
        int i0 = faces[3 * iBs + 0], i1 = faces[3 * iBs + 1], i2 = faces[3 * iBs + 2];
        float ax = verts[3 * i0 + 0], ay = verts[3 * i0 + 1], az = verts[3 * i0 + 2];
        float bx = verts[3 * i1 + 0], by = verts[3 * i1 + 1], bz = verts[3 * i1 + 2];
        float cx = verts[3 * i2 + 0], cy = verts[3 * i2 + 1], cz = verts[3 * i2 + 2];
        ciBx = (ax + bx + cx) * third;
        ciBy = (ay + by + cy) * third;
        ciBz = (az + bz + cz) * third;
#pragma unroll
        for (int s = 0; s < SS; ++s) {
            float al = alpha[iBs * SS + s];
            float be = beta[iBs * SS + s];
            float ga = 1.0f - al - be;
            sxB[s] = al * ax + be * bx + ga * cx;
            syB[s] = al * ay + be * by + ga * cy;
            szB[s] = al * az + be * bz + ga * cz;
        }
    }

    // ---- phase 1: distance tests against register-resident centroids ----
    int wlenA = 0, wlenB = 0;
    const int wbaseA = wave * SEG;
    const int wbaseB = (4 + wave) * SEG;
#pragma unroll
    for (int t = 0; t < 4; ++t) {
        if (t * BLOCK >= F) break;               // uniform
        int j = t * BLOCK + tid;
        float dxA = ciAx - cxR[t], dyA = ciAy - cyR[t], dzA = ciAz - czR[t];
        float d2A = dxA * dxA + dyA * dyA + dzA * dzA;
        bool passA = (j < F) && (d2A < 1.0f) && (j != iA);
        float dxB = ciBx - cxR[t], dyB = ciBy - cyR[t], dzB = ciBz - czR[t];
        float d2B = dxB * dxB + dyB * dyB + dzB * dzB;
        bool passB = hasB && (j < F) && (d2B < 1.0f) && (j != iB);

        unsigned long long mA = __ballot(passA);
        if (passA) s_queue[wbaseA + wlenA + mbcnt64(mA)] = j;
        wlenA += __popcll(mA);
        unsigned long long mB = __ballot(passB);
        if (passB) s_queue[wbaseB + wlenB + mbcnt64(mB)] = j;
        wlenB += __popcll(mB);
    }

    __syncthreads();   // s_gg fully written before walks read it

    // ---- phase 2: pipelined walks (gg from LDS) ----
    int countA = walk_queue<SS>(s_queue, wbaseA, wlenA, lane, s_gg, sxA, syA, szA);
    int countB = walk_queue<SS>(s_queue, wbaseB, wlenB, lane, s_gg, sxB, syB, szB);

    // ---- epilogue: reduce counts, publish complement-pair partials ----
    for (int off = 32; off > 0; off >>= 1) {
        countA += __shfl_down(countA, off, 64);
        countB += __shfl_down(countB, off, 64);
    }
    if (lane == 0) { wave_cnt[0][wave] = countA; wave_cnt[1][wave] = countB; }
    __syncthreads();                              // also: all walks done
    if (tid == 0) {
        int tA = 0, tB = 0;
#pragma unroll
        for (int w = 0; w < BLOCK / 64; ++w) { tA += wave_cnt[0][w]; tB += wave_cnt[1][w]; }
        unsigned int va = __float_as_uint(face_probs[iA] * (float)tA);
        __hip_atomic_store(&arrA[iA], va, __ATOMIC_RELAXED, __HIP_MEMORY_SCOPE_AGENT);
        __hip_atomic_store(&arrB[iA], ~va, __ATOMIC_RELAXED, __HIP_MEMORY_SCOPE_AGENT);
        if (hasB) {
            unsigned int vb = __float_as_uint(face_probs[iB] * (float)tB);
            __hip_atomic_store(&arrA[iB], vb, __ATOMIC_RELAXED, __HIP_MEMORY_SCOPE_AGENT);
            __hip_atomic_store(&arrB[iB], ~vb, __ATOMIC_RELAXED, __HIP_MEMORY_SCOPE_AGENT);
        }
    }

    if (blockIdx.x != 0) return;

    // ---- block 0: poll validated partials, then reduce in the exact FP
    //      order of the old reduce_kernel ----
    float* s_vals = (float*)smem;                 // reuse s_gg region (walks done)
    for (int i = tid; i < F; i += BLOCK) {
        unsigned int a, b;
        do {
            a = __hip_atomic_load(&arrA[i], __ATOMIC_RELAXED, __HIP_MEMORY_SCOPE_AGENT);
            b = __hip_atomic_load(&arrB[i], __ATOMIC_RELAXED, __HIP_MEMORY_SCOPE_AGENT);
        } while (b != ~a);
        s_vals[i] = __uint_as_float(a);
    }
    __syncthreads();

    float sum = 0.0f;
    int F4 = F >> 2;
    for (int f = tid; f < F4; f += BLOCK) {
        float x = s_vals[4 * f + 0], y = s_vals[4 * f + 1];
        float z = s_vals[4 * f + 2], w = s_vals[4 * f + 3];
        sum += (x + y) + (z + w);
    }
    for (int f = (F4 << 2) + tid; f < F; f += BLOCK) sum += s_vals[f];
    for (int off = 32; off > 0; off >>= 1)
        sum += __shfl_down(sum, off, 64);
    if (lane == 0) wave_sum[wave] = sum;
    __syncthreads();
    if (tid == 0) {
        float tot = 0.0f;
#pragma unroll
        for (int w = 0; w < BLOCK / 64; ++w) tot += wave_sum[w];
        out[0] = tot * invF;
    }
}

// ---------------------------------------------------------------------------
// Generic-S fallback (samples in LDS), used only if S != 10 or F > 1024.
// ---------------------------------------------------------------------------
#define MAXS_G 64
__global__ void __launch_bounds__(BLOCK)
pair_kernel_generic(const float4* __restrict__ cent,
                    const float4* __restrict__ gg,
                    const float4* __restrict__ spts,
                    const float* __restrict__ face_probs,
                    int F, int S,
                    float* __restrict__ partial) {
    const int i = blockIdx.x;
    const int tid = threadIdx.x;
    __shared__ float s_x[MAXS_G], s_y[MAXS_G], s_z[MAXS_G];
    for (int s = tid; s < S; s += BLOCK) {
        float4 p = spts[(long long)i * S + s];
        s_x[s] = p.x; s_y[s] = p.y; s_z[s] = p.z;
    }
    __syncthreads();
    const float4 ci = cent[i];

    int count = 0;
    for (int j = tid; j < F; j += BLOCK) {
        float4 cj = cent[j];
        float dx = ci.x - cj.x, dy = ci.y - cj.y, dz = ci.z - cj.z;
        float d2 = dx * dx + dy * dy + dz * dz;
        if ((d2 < 1.0f) && (j != i)) {
            float4 a = gg[2 * j];
            float4 b = gg[2 * j + 1];
            float best = -1.0f;
            for (int s = 0; s < S; ++s) {
                float vv = fmaf(s_z[s], a.z, fmaf(s_y[s], a.y, fmaf(s_x[s], a.x, a.w)));
                float ww = fmaf(s_z[s], b.z, fmaf(s_y[s], b.y, fmaf(s_x[s], b.x, b.w)));
                float uu = 1.0f - vv - ww;
                best = fmaxf(best, fminf(uu, fminf(vv, ww)));
            }
            count += (best >= 0.0f) ? 1 : 0;
        }
    }

    for (int off = 32; off > 0; off >>= 1)
        count += __shfl_down(count, off, 64);
    __shared__ int wave_cnt[BLOCK / 64];
    if ((tid & 63) == 0) wave_cnt[tid >> 6] = count;
    __syncthreads();
    if (tid == 0) {
        int tot = 0;
#pragma unroll
        for (int w = 0; w < BLOCK / 64; ++w) tot += wave_cnt[w];
        partial[i] = face_probs[i] * (float)tot;
    }
}

__global__ void __launch_bounds__(BLOCK)
reduce_kernel(const float* __restrict__ partial, float* __restrict__ out,
              int F, float invF) {
    const int tid = threadIdx.x;
    float sum = 0.0f;
    int F4 = F >> 2;
    const float4* p4 = (const float4*)partial;
    for (int f = tid; f < F4; f += BLOCK) {
        float4 v = p4[f];
        sum += (v.x + v.y) + (v.z + v.w);
    }
    for (int f = (F4 << 2) + tid; f < F; f += BLOCK) sum += partial[f];
    for (int off = 32; off > 0; off >>= 1)
        sum += __shfl_down(sum, off, 64);
    __shared__ float wave_sum[BLOCK / 64];
    if ((tid & 63) == 0) wave_sum[tid >> 6] = sum;
    __syncthreads();
    if (tid == 0) {
        float tot = 0.0f;
#pragma unroll
        for (int w = 0; w < BLOCK / 64; ++w) tot += wave_sum[w];
        out[0] = tot * invF;
    }
}

extern "C" void kernel_launch(void* const* d_in, const int* in_sizes, int n_in,
                              void* d_out, int out_size, void* d_ws, size_t ws_size,
                              hipStream_t stream) {
    const float* vertices   = (const float*)d_in[0];
    const int*   faces      = (const int*)d_in[1];
    const float* face_probs = (const float*)d_in[2];
    const float* alpha      = (const float*)d_in[3];
    const float* beta       = (const float*)d_in[4];
    float* out = (float*)d_out;

    const int F = in_sizes[2];
    const int S = in_sizes[3] / F;

    if (S == 10 && F >= 1 && F <= 1024) {
        int SEG = ((F + BLOCK - 1) / BLOCK) * 64;
        size_t lds = (size_t)2 * F * sizeof(float4) + (size_t)(8 * SEG) * sizeof(int);
        int nblk = (F + 1) / 2;
        float invF = 1.0f / (float)F;
        unsigned int* arrA = (unsigned int*)d_ws;
        unsigned int* arrB = arrA + F;

        // Round 3: PLAIN launch (not cooperative). The spin protocol is
        // deadlock-free without co-residency; coop launch only added
        // validation/sync overhead on the launch path.
        fused2_kernel<10><<<nblk, BLOCK, lds, stream>>>(
            vertices, faces, face_probs, alpha, beta, F, SEG,
            arrA, arrB, out, invF);
        return;
    }

    // ---- fallback: verified 3-kernel path (generic shapes) ----
    char* ws = (char*)d_ws;
    float4* cent = (float4*)ws;
    float4* gg   = cent + F;
    float4* spts = gg + 2 * F;
    float*  partial = (float*)(spts + (long long)F * S);

    int nfs = F * S;
    face_pre_kernel<<<(nfs + BLOCK - 1) / BLOCK, BLOCK, 0, stream>>>(
        vertices, faces, alpha, beta, F, S, cent, gg, spts);
    pair_kernel_generic<<<F, BLOCK, 0, stream>>>(
        cent, gg, spts, face_probs, F, S, partial);
    reduce_kernel<<<1, BLOCK, 0, stream>>>(partial, out, F, 1.0f / (float)F);
}

// Round 4
// 75.427 us; speedup vs baseline: 1.1667x; 1.1667x over previous
//
#include <hip/hip_runtime.h>

#define BLOCK 256

__device__ __forceinline__ int mbcnt64(unsigned long long m) {
    return __builtin_amdgcn_mbcnt_hi((unsigned int)(m >> 32),
           __builtin_amdgcn_mbcnt_lo((unsigned int)m, 0));
}

// ---------------------------------------------------------------------------
// Kernel 1: per-face precompute, one thread per (f,s) (wide launch).
//   cent[f]       = centroid (xyz)
//   gg[2f+0] = (gv.xyz, cv):  v = dot(p,gv)+cv      } interleaved: both
//   gg[2f+1] = (gw.xyz, cw):  w = dot(p,gw)+cw      } fragments in one line
//   spts[f*S+s]   = sample point s of face f
// ---------------------------------------------------------------------------
__global__ void face_pre_kernel(const float* __restrict__ verts,
                                const int* __restrict__ faces,
                                const float* __restrict__ alpha,
                                const float* __restrict__ beta,
                                int F, int S,
                                float4* __restrict__ cent,
                                float4* __restrict__ gg,
                                float4* __restrict__ spts) {
    int idx = blockIdx.x * blockDim.x + threadIdx.x;
    if (idx >= F * S) return;
    int f = idx / S;
    int s = idx - f * S;

    int i0 = faces[3 * f + 0];
    int i1 = faces[3 * f + 1];
    int i2 = faces[3 * f + 2];
    float ax = verts[3 * i0 + 0], ay = verts[3 * i0 + 1], az = verts[3 * i0 + 2];
    float bx = verts[3 * i1 + 0], by = verts[3 * i1 + 1], bz = verts[3 * i1 + 2];
    float cx = verts[3 * i2 + 0], cy = verts[3 * i2 + 1], cz = verts[3 * i2 + 2];

    float al = alpha[idx];
    float be = beta[idx];
    float ga = 1.0f - al - be;
    spts[idx] = make_float4(al * ax + be * bx + ga * cx,
                            al * ay + be * by + ga * cy,
                            al * az + be * bz + ga * cz, 0.0f);

    if (s == 0) {
        float e0x = bx - ax, e0y = by - ay, e0z = bz - az;
        float e1x = cx - ax, e1y = cy - ay, e1z = cz - az;

        float d00 = e0x * e0x + e0y * e0y + e0z * e0z;
        float d01 = e0x * e1x + e0y * e1y + e0z * e1z;
        float d11 = e1x * e1x + e1y * e1y + e1z * e1z;
        float inv = 1.0f / (d00 * d11 - d01 * d01);
        float A = d11 * inv, B = d01 * inv, C = d00 * inv;

        float w1e0 = ax * e0x + ay * e0y + az * e0z;
        float w1e1 = ax * e1x + ay * e1y + az * e1z;

        const float third = 1.0f / 3.0f;
        cent[f] = make_float4((ax + bx + cx) * third,
                              (ay + by + cy) * third,
                              (az + bz + cz) * third, 0.0f);
        gg[2 * f + 0] = make_float4(A * e0x - B * e1x, A * e0y - B * e1y,
                                    A * e0z - B * e1z, B * w1e1 - A * w1e0);
        gg[2 * f + 1] = make_float4(C * e1x - B * e0x, C * e1y - B * e0y,
                                    C * e1z - B * e0z, B * w1e0 - C * w1e1);
    }
}

// ---------------------------------------------------------------------------
// Depth-2 pipelined walk of one wave-private queue segment.
// ---------------------------------------------------------------------------
template <int SS>
__device__ __forceinline__ int walk_queue(const int* s_queue, int wbase, int wlen,
                                          int lane,
                                          const float4* __restrict__ gg,
                                          const float* sx, const float* sy,
                                          const float* sz) {
    int count = 0;
    const int nIter = (wlen + 63) >> 6;
    bool  v_cur = lane < wlen;
    int   j_cur = v_cur ? s_queue[wbase + lane] : 0;
    float4 a_cur, b_cur;
    if (v_cur) { a_cur = gg[2 * j_cur]; b_cur = gg[2 * j_cur + 1]; }
    for (int t = 0; t < nIter; ++t) {
        int   k_n = lane + (t + 1) * 64;
        bool  v_n = k_n < wlen;
        int   j_n = v_n ? s_queue[wbase + k_n] : 0;
        float4 a_n, b_n;
        if (v_n) { a_n = gg[2 * j_n]; b_n = gg[2 * j_n + 1]; }
        if (v_cur) {
            float best = -1.0f;
#pragma unroll
            for (int s = 0; s < SS; ++s) {
                float vv = fmaf(sz[s], a_cur.z,
                            fmaf(sy[s], a_cur.y, fmaf(sx[s], a_cur.x, a_cur.w)));
                float ww = fmaf(sz[s], b_cur.z,
                            fmaf(sy[s], b_cur.y, fmaf(sx[s], b_cur.x, b_cur.w)));
                float uu = 1.0f - vv - ww;
                best = fmaxf(best, fminf(uu, fminf(vv, ww)));
            }
            count += (best >= 0.0f) ? 1 : 0;
        }
        v_cur = v_n; a_cur = a_n; b_cur = b_n;
    }
    return count;
}

// ---------------------------------------------------------------------------
// Kernel 2: pair kernel, TWO i's per block, wave-private compaction,
// barrier-free main body, interleaved gg gathers.
//   Phase 1: one cent stream tested against BOTH centroids (load cost
//            amortized 2x; global cent traffic halved vs R10).
//   Phase 2: two pipelined queue walks (one per i).
// Dynamic LDS: 8 * SEG ints (4 waves x 2 queues).
// ---------------------------------------------------------------------------
template <int SS>
__global__ void __launch_bounds__(BLOCK)
pair_kernel(const float4* __restrict__ cent,
            const float4* __restrict__ gg,
            const float4* __restrict__ spts,
            const float* __restrict__ face_probs,
            int F, int SEG,
            float* __restrict__ partial) {
    const int iA = blockIdx.x * 2;
    const int iB = iA + 1;
    const bool hasB = (iB < F);
    const int iBs = hasB ? iB : iA;          // safe index for loads
    const int tid = threadIdx.x;
    const int lane = tid & 63;
    const int wave = tid >> 6;

    extern __shared__ int s_queue[];          // 8 * SEG ints
    __shared__ int wave_cnt[2][BLOCK / 64];
    const int wbaseA = wave * SEG;
    const int wbaseB = (4 + wave) * SEG;

    // ---- uniform prologue (scalar loads; iA/iB block-uniform) ----
    const float4 ciA = cent[iA];
    const float4 ciB = cent[iBs];
    float sxA[SS], syA[SS], szA[SS], sxB[SS], syB[SS], szB[SS];
#pragma unroll
    for (int s = 0; s < SS; ++s) {
        float4 p = spts[iA * SS + s];
        sxA[s] = p.x; syA[s] = p.y; szA[s] = p.z;
        float4 q = spts[iBs * SS + s];
        sxB[s] = q.x; syB[s] = q.y; szB[s] = q.z;
    }

    // ---- phase 1: one cent stream, two dist tests, two private queues ----
    int wlenA = 0, wlenB = 0;
    float4 c_next = (tid < F) ? cent[tid]
                              : make_float4(1e30f, 1e30f, 1e30f, 0.0f);
    for (int k = 0; k < F; k += BLOCK) {
        int j = k + tid;
        float4 c = c_next;
        int jn = k + BLOCK + tid;
        if (jn < F) c_next = cent[jn];         // prefetch next iter
        float dxA = ciA.x - c.x, dyA = ciA.y - c.y, dzA = ciA.z - c.z;
        float d2A = dxA * dxA + dyA * dyA + dzA * dzA;
        bool passA = (j < F) && (d2A < 1.0f) && (j != iA);
        float dxB = ciB.x - c.x, dyB = ciB.y - c.y, dzB = ciB.z - c.z;
        float d2B = dxB * dxB + dyB * dyB + dzB * dzB;
        bool passB = hasB && (j < F) && (d2B < 1.0f) && (j != iB);

        unsigned long long mA = __ballot(passA);
        if (passA) s_queue[wbaseA + wlenA + mbcnt64(mA)] = j;
        wlenA += __popcll(mA);
        unsigned long long mB = __ballot(passB);
        if (passB) s_queue[wbaseB + wlenB + mbcnt64(mB)] = j;
        wlenB += __popcll(mB);
    }

    // ---- phase 2: pipelined walks ----
    int countA = walk_queue<SS>(s_queue, wbaseA, wlenA, lane, gg, sxA, syA, szA);
    int countB = walk_queue<SS>(s_queue, wbaseB, wlenB, lane, gg, sxB, syB, szB);

    // ---- epilogue: shuffle reduce both counts -> LDS -> two stores ----
    for (int off = 32; off > 0; off >>= 1) {
        countA += __shfl_down(countA, off, 64);
        countB += __shfl_down(countB, off, 64);
    }
    if (lane == 0) { wave_cnt[0][wave] = countA; wave_cnt[1][wave] = countB; }
    __syncthreads();
    if (tid == 0) {
        int tA = 0, tB = 0;
#pragma unroll
        for (int w = 0; w < BLOCK / 64; ++w) { tA += wave_cnt[0][w]; tB += wave_cnt[1][w]; }
        partial[iA] = face_probs[iA] * (float)tA;
        if (hasB) partial[iB] = face_probs[iB] * (float)tB;
    }
}

// ---------------------------------------------------------------------------
// Generic-S fallback (samples in LDS), used only if S != 10.
// ---------------------------------------------------------------------------
#define MAXS_G 64
__global__ void __launch_bounds__(BLOCK)
pair_kernel_generic(const float4* __restrict__ cent,
                    const float4* __restrict__ gg,
                    const float4* __restrict__ spts,
                    const float* __restrict__ face_probs,
                    int F, int S,
                    float* __restrict__ partial) {
    const int i = blockIdx.x;
    const int tid = threadIdx.x;
    __shared__ float s_x[MAXS_G], s_y[MAXS_G], s_z[MAXS_G];
    for (int s = tid; s < S; s += BLOCK) {
        float4 p = spts[(long long)i * S + s];
        s_x[s] = p.x; s_y[s] = p.y; s_z[s] = p.z;
    }
    __syncthreads();
    const float4 ci = cent[i];

    int count = 0;
    for (int j = tid; j < F; j += BLOCK) {
        float4 cj = cent[j];
        float dx = ci.x - cj.x, dy = ci.y - cj.y, dz = ci.z - cj.z;
        float d2 = dx * dx + dy * dy + dz * dz;
        if ((d2 < 1.0f) && (j != i)) {
            float4 a = gg[2 * j];
            float4 b = gg[2 * j + 1];
            float best = -1.0f;
            for (int s = 0; s < S; ++s) {
                float vv = fmaf(s_z[s], a.z, fmaf(s_y[s], a.y, fmaf(s_x[s], a.x, a.w)));
                float ww = fmaf(s_z[s], b.z, fmaf(s_y[s], b.y, fmaf(s_x[s], b.x, b.w)));
                float uu = 1.0f - vv - ww;
                best = fmaxf(best, fminf(uu, fminf(vv, ww)));
            }
            count += (best >= 0.0f) ? 1 : 0;
        }
    }

    for (int off = 32; off > 0; off >>= 1)
        count += __shfl_down(count, off, 64);
    __shared__ int wave_cnt[BLOCK / 64];
    if ((tid & 63) == 0) wave_cnt[tid >> 6] = count;
    __syncthreads();
    if (tid == 0) {
        int tot = 0;
#pragma unroll
        for (int w = 0; w < BLOCK / 64; ++w) tot += wave_cnt[w];
        partial[i] = face_probs[i] * (float)tot;
    }
}

// ---------------------------------------------------------------------------
// Kernel 3: reduce partial[0..F) -> out[0] = sum / F. Single block, float4.
// ---------------------------------------------------------------------------
__global__ void __launch_bounds__(BLOCK)
reduce_kernel(const float* __restrict__ partial, float* __restrict__ out,
              int F, float invF) {
    const int tid = threadIdx.x;
    float sum = 0.0f;
    int F4 = F >> 2;
    const float4* p4 = (const float4*)partial;
    for (int f = tid; f < F4; f += BLOCK) {
        float4 v = p4[f];
        sum += (v.x + v.y) + (v.z + v.w);
    }
    for (int f = (F4 << 2) + tid; f < F; f += BLOCK) sum += partial[f];
    for (int off = 32; off > 0; off >>= 1)
        sum += __shfl_down(sum, off, 64);
    __shared__ float wave_sum[BLOCK / 64];
    if ((tid & 63) == 0) wave_sum[tid >> 6] = sum;
    __syncthreads();
    if (tid == 0) {
        float tot = 0.0f;
#pragma unroll
        for (int w = 0; w < BLOCK / 64; ++w) tot += wave_sum[w];
        out[0] = tot * invF;
    }
}

extern "C" void kernel_launch(void* const* d_in, const int* in_sizes, int n_in,
                              void* d_out, int out_size, void* d_ws, size_t ws_size,
                              hipStream_t stream) {
    const float* vertices   = (const float*)d_in[0];
    const int*   faces      = (const int*)d_in[1];
    const float* face_probs = (const float*)d_in[2];
    const float* alpha      = (const float*)d_in[3];
    const float* beta       = (const float*)d_in[4];
    float* out = (float*)d_out;

    const int F = in_sizes[2];
    const int S = in_sizes[3] / F;

    // Workspace: cent[F], gg[2F], spts[F*S] (float4), partial[F].
    char* ws = (char*)d_ws;
    float4* cent = (float4*)ws;
    float4* gg   = cent + F;
    float4* spts = gg + 2 * F;
    float*  partial = (float*)(spts + (long long)F * S);

    int nfs = F * S;
    face_pre_kernel<<<(nfs + BLOCK - 1) / BLOCK, BLOCK, 0, stream>>>(
        vertices, faces, alpha, beta, F, S, cent, gg, spts);

    if (S == 10) {
        int SEG = ((F + BLOCK - 1) / BLOCK) * 64;  // per-wave queue capacity
        size_t lds = (size_t)(8 * SEG) * sizeof(int);
        int nblk = (F + 1) / 2;
        pair_kernel<10><<<nblk, BLOCK, lds, stream>>>(
            cent, gg, spts, face_probs, F, SEG, partial);
    } else {
        pair_kernel_generic<<<F, BLOCK, 0, stream>>>(
            cent, gg, spts, face_probs, F, S, partial);
    }

    reduce_kernel<<<1, BLOCK, 0, stream>>>(partial, out, F, 1.0f / (float)F);
}